// Round 1
// baseline (1287.626 us; speedup 1.0000x reference)
//
#include <hip/hip_runtime.h>
#include <hip/hip_fp16.h>
#include <cstdint>

#define T_SEQ 2048
#define DMODEL 2048
#define NHEADS 16
#define HDIM 128
#define BT 4096      // B*T
#define NH 2048      // N*H

typedef _Float16 f16;
typedef _Float16 f16x8 __attribute__((ext_vector_type(8)));
typedef float f32x4 __attribute__((ext_vector_type(4)));

typedef __attribute__((address_space(1))) const void* gldg_t;
typedef __attribute__((address_space(3))) void* slds_t;

// ---------------- elementwise cast f32 -> f16 (8 elems/thread) ----------------
__global__ __launch_bounds__(256)
void cast_f32_f16(const float* __restrict__ in, f16* __restrict__ out, int n8) {
  int i = blockIdx.x * blockDim.x + threadIdx.x;
  if (i >= n8) return;
  const float4* p = (const float4*)in + (size_t)i * 2;
  float4 a = p[0], b = p[1];
  f16x8 h;
  h[0] = (f16)a.x; h[1] = (f16)a.y; h[2] = (f16)a.z; h[3] = (f16)a.w;
  h[4] = (f16)b.x; h[5] = (f16)b.y; h[6] = (f16)b.z; h[7] = (f16)b.w;
  *((f16x8*)out + i) = h;
}

// ---------------- weight transpose + cast: W[d][nh] f32 -> Wt[nh][d] f16 ------
__global__ __launch_bounds__(256)
void transpose_cast_w(const float* __restrict__ in, f16* __restrict__ out) {
  __shared__ float tile[32][33];
  int c0 = blockIdx.x * 32, r0 = blockIdx.y * 32;
  int x = threadIdx.x, y = threadIdx.y;
#pragma unroll
  for (int j = 0; j < 32; j += 8)
    tile[y + j][x] = in[(size_t)(r0 + y + j) * DMODEL + c0 + x];
  __syncthreads();
#pragma unroll
  for (int j = 0; j < 32; j += 8)
    out[(size_t)(c0 + y + j) * DMODEL + r0 + x] = (f16)tile[x][y + j];
}

// ---------------- V transpose per head: V[b*T+s][n*H+h] -> VT[z][h][s] --------
__global__ __launch_bounds__(256)
void transpose_v(const f16* __restrict__ v, f16* __restrict__ vt) {
  __shared__ f16 tile[32][34];
  int z = blockIdx.z;          // b*16 + n
  int b = z >> 4, n = z & 15;
  int s0 = blockIdx.x * 32, h0 = blockIdx.y * 32;
  int x = threadIdx.x, y = threadIdx.y;
  const f16* src = v + (size_t)(b * T_SEQ + s0) * NH + n * HDIM + h0;
#pragma unroll
  for (int j = 0; j < 32; j += 8)
    tile[y + j][x] = src[(size_t)(y + j) * NH + x];   // [s_local][h_local]
  __syncthreads();
  f16* dst = vt + ((size_t)z * HDIM + h0) * T_SEQ + s0;
#pragma unroll
  for (int j = 0; j < 32; j += 8)
    dst[(size_t)(y + j) * T_SEQ + x] = tile[x][y + j];
}

// ---------------- row softmax, in-place on fp32 logits ------------------------
__global__ __launch_bounds__(256)
void softmax_rows(float* __restrict__ p_all) {
  __shared__ float red[8];
  float* p = p_all + (size_t)blockIdx.x * T_SEQ;
  int t = threadIdx.x;
  float4* pv = (float4*)p;
  float4 v0 = pv[2 * t], v1 = pv[2 * t + 1];
  float m = fmaxf(fmaxf(fmaxf(v0.x, v0.y), fmaxf(v0.z, v0.w)),
                  fmaxf(fmaxf(v1.x, v1.y), fmaxf(v1.z, v1.w)));
#pragma unroll
  for (int d = 1; d < 64; d <<= 1) m = fmaxf(m, __shfl_xor(m, d));
  if ((t & 63) == 0) red[t >> 6] = m;
  __syncthreads();
  m = fmaxf(fmaxf(red[0], red[1]), fmaxf(red[2], red[3]));
  float e0 = __expf(v0.x - m), e1 = __expf(v0.y - m);
  float e2 = __expf(v0.z - m), e3 = __expf(v0.w - m);
  float e4 = __expf(v1.x - m), e5 = __expf(v1.y - m);
  float e6 = __expf(v1.z - m), e7 = __expf(v1.w - m);
  float s = ((e0 + e1) + (e2 + e3)) + ((e4 + e5) + (e6 + e7));
#pragma unroll
  for (int d = 1; d < 64; d <<= 1) s += __shfl_xor(s, d);
  if ((t & 63) == 0) red[4 + (t >> 6)] = s;
  __syncthreads();
  s = (red[4] + red[5]) + (red[6] + red[7]);
  float inv = 1.0f / s;
  v0.x = e0 * inv; v0.y = e1 * inv; v0.z = e2 * inv; v0.w = e3 * inv;
  v1.x = e4 * inv; v1.y = e5 * inv; v1.z = e6 * inv; v1.w = e7 * inv;
  pv[2 * t] = v0; pv[2 * t + 1] = v1;
}

// ---------------- GEMM staging helpers ---------------------------------------
// LDS tile: [128 rows][32 k] f16, linear; chunk ci = row*4 + slot (16B chunks).
__device__ __forceinline__ void stage_f16t(const f16* __restrict__ tilebase, int lda,
                                           int k0, f16* ldsbuf, int w, int l) {
#pragma unroll
  for (int half = 0; half < 2; ++half) {
    int ci = half * 256 + w * 64 + l;
    int r = ci >> 2, sl = ci & 3;
    const f16* src = tilebase + (size_t)r * lda + k0 + sl * 8;
    __builtin_amdgcn_global_load_lds((gldg_t)src,
                                     (slds_t)(ldsbuf + half * 2048 + w * 512),
                                     16, 0, 0);
  }
}

__device__ __forceinline__ void stage_f32t(const float* __restrict__ tilebase, int lda,
                                           int k0, f16* ldsbuf, int w, int l) {
#pragma unroll
  for (int half = 0; half < 2; ++half) {
    int ci = half * 256 + w * 64 + l;
    int r = ci >> 2, sl = ci & 3;
    const float* src = tilebase + (size_t)r * lda + k0 + sl * 8;
    float4 a = *(const float4*)src;
    float4 b = *(const float4*)(src + 4);
    f16x8 h;
    h[0] = (f16)a.x; h[1] = (f16)a.y; h[2] = (f16)a.z; h[3] = (f16)a.w;
    h[4] = (f16)b.x; h[5] = (f16)b.y; h[6] = (f16)b.z; h[7] = (f16)b.w;
    *(f16x8*)(ldsbuf + (size_t)ci * 8) = h;
  }
}

// ---------------- 128x128-tile GEMM, C = A * B^T (+epilogue) -------------------
// A: [M][K] (f16, or f32 for MODE 2), B: [N][K] f16.
// MODE 0: C f16 = (acc + bias[col]) * alpha          (QKV projection)
// MODE 1: C f32 = acc + bias2d[row*T + col]          (logits + additive bias)
// MODE 2: C f16 = acc                                 (PV; A is f32 probs)
// MODE 3: C f32 = acc + bias[col]                    (output projection)
template <int MODE>
__global__ __launch_bounds__(256)
void gemm128(const void* __restrict__ Av, const f16* __restrict__ Bmat,
             void* __restrict__ Cv, const float* __restrict__ bias,
             float alpha, int K, int lda, int ldb, int ldc,
             long long sA_b, long long sA_n, long long sB_b, long long sB_n,
             long long sC_b, long long sC_n) {
  __shared__ __align__(16) f16 As[2][128 * 32];
  __shared__ __align__(16) f16 Bs[2][128 * 32];

  int z = blockIdx.z, zb = z >> 4, zn = z & 15;
  int cn = blockIdx.x * 128, rm = blockIdx.y * 128;
  int tid = threadIdx.x, w = tid >> 6, l = tid & 63;

  const f16* Btile = Bmat + (size_t)(zb * sB_b + zn * sB_n) + (size_t)cn * ldb;
  const f16* Atile16 = nullptr;
  const float* Atile32 = nullptr;
  if constexpr (MODE == 2)
    Atile32 = (const float*)Av + (size_t)(zb * sA_b + zn * sA_n) + (size_t)rm * lda;
  else
    Atile16 = (const f16*)Av + (size_t)(zb * sA_b + zn * sA_n) + (size_t)rm * lda;

  f32x4 zero4 = {0.0f, 0.0f, 0.0f, 0.0f};
  f32x4 acc[4][4];
#pragma unroll
  for (int i = 0; i < 4; ++i)
#pragma unroll
    for (int j = 0; j < 4; ++j) acc[i][j] = zero4;

  if constexpr (MODE == 2) stage_f32t(Atile32, lda, 0, As[0], w, l);
  else                     stage_f16t(Atile16, lda, 0, As[0], w, l);
  stage_f16t(Btile, ldb, 0, Bs[0], w, l);
  __syncthreads();

  int wm = w >> 1, wn = w & 1;
  int lr = l & 15, lg = l >> 4;
  int aoff[4], boff[4];
#pragma unroll
  for (int i = 0; i < 4; ++i) {
    aoff[i] = (wm * 64 + i * 16 + lr) * 32 + lg * 8;
    boff[i] = (wn * 64 + i * 16 + lr) * 32 + lg * 8;
  }

  int nk = K >> 5;
  for (int kt = 0; kt < nk; ++kt) {
    int cur = kt & 1;
    if (kt + 1 < nk) {
      int k0 = (kt + 1) << 5;
      if constexpr (MODE == 2) stage_f32t(Atile32, lda, k0, As[cur ^ 1], w, l);
      else                     stage_f16t(Atile16, lda, k0, As[cur ^ 1], w, l);
      stage_f16t(Btile, ldb, k0, Bs[cur ^ 1], w, l);
    }
    f16x8 af[4], bf[4];
#pragma unroll
    for (int i = 0; i < 4; ++i) af[i] = *(const f16x8*)&As[cur][aoff[i]];
#pragma unroll
    for (int i = 0; i < 4; ++i) bf[i] = *(const f16x8*)&Bs[cur][boff[i]];
#pragma unroll
    for (int i = 0; i < 4; ++i)
#pragma unroll
      for (int j = 0; j < 4; ++j)
        acc[i][j] = __builtin_amdgcn_mfma_f32_16x16x32_f16(af[i], bf[j], acc[i][j], 0, 0, 0);
    __syncthreads();
  }

  size_t coff = (size_t)(zb * sC_b + zn * sC_n);
#pragma unroll
  for (int i = 0; i < 4; ++i) {
#pragma unroll
    for (int j = 0; j < 4; ++j) {
      int row = rm + wm * 64 + i * 16 + lg * 4 + j;
#pragma unroll
      for (int jn = 0; jn < 4; ++jn) {
        int col = cn + wn * 64 + jn * 16 + lr;
        float v = acc[i][jn][j];
        if constexpr (MODE == 0) {
          ((f16*)Cv)[coff + (size_t)row * ldc + col] = (f16)((v + bias[col]) * alpha);
        } else if constexpr (MODE == 1) {
          ((float*)Cv)[coff + (size_t)row * ldc + col] = v + bias[(size_t)row * T_SEQ + col];
        } else if constexpr (MODE == 2) {
          ((f16*)Cv)[coff + (size_t)row * ldc + col] = (f16)v;
        } else {
          ((float*)Cv)[coff + (size_t)row * ldc + col] = v + bias[col];
        }
      }
    }
  }
}

// ------------------------------------------------------------------------------
extern "C" void kernel_launch(void* const* d_in, const int* in_sizes, int n_in,
                              void* d_out, int out_size, void* d_ws, size_t ws_size,
                              hipStream_t stream) {
  const float* query  = (const float*)d_in[0];
  const float* bias2d = (const float*)d_in[1];
  const float* qw = (const float*)d_in[2];
  const float* qb = (const float*)d_in[3];
  const float* kw = (const float*)d_in[4];
  const float* kb = (const float*)d_in[5];
  const float* vw = (const float*)d_in[6];
  const float* vb = (const float*)d_in[7];
  const float* ow = (const float*)d_in[8];
  const float* ob = (const float*)d_in[9];

  float* out_data  = (float*)d_out;                          // [BT][D] fp32
  float* out_probs = (float*)d_out + (size_t)BT * DMODEL;    // [32][T][T] fp32

  f16* X   = (f16*)d_ws;                       // [BT][D]
  f16* Wqt = X   + (size_t)BT * DMODEL;        // [NH][D]
  f16* Wkt = Wqt + (size_t)DMODEL * NH;
  f16* Wvt = Wkt + (size_t)DMODEL * NH;
  f16* Wo  = Wvt + (size_t)DMODEL * NH;        // [D][NH] (no transpose needed)
  f16* Qb  = Wo  + (size_t)DMODEL * NH;        // [BT][NH]
  f16* Kb  = Qb  + (size_t)BT * NH;
  f16* Vb  = Kb  + (size_t)BT * NH;
  f16* VT  = Vb  + (size_t)BT * NH;            // [32][H][T]
  f16* CTX = VT  + (size_t)BT * NH;            // [BT][NH]

  dim3 tb(32, 8);

  // 1. casts / transposes of inputs
  cast_f32_f16<<<4096, 256, 0, stream>>>(query, X, BT * DMODEL / 8);
  cast_f32_f16<<<2048, 256, 0, stream>>>(ow, Wo, DMODEL * NH / 8);
  transpose_cast_w<<<dim3(64, 64), tb, 0, stream>>>(qw, Wqt);
  transpose_cast_w<<<dim3(64, 64), tb, 0, stream>>>(kw, Wkt);
  transpose_cast_w<<<dim3(64, 64), tb, 0, stream>>>(vw, Wvt);

  // 2. QKV projections (scale folded into Q epilogue)
  const float alphaq = 0.08838834764831845f;  // 1/sqrt(128)
  gemm128<0><<<dim3(16, 32, 1), 256, 0, stream>>>(X, Wqt, Qb, qb, alphaq,
      DMODEL, DMODEL, DMODEL, NH, 0, 0, 0, 0, 0, 0);
  gemm128<0><<<dim3(16, 32, 1), 256, 0, stream>>>(X, Wkt, Kb, kb, 1.0f,
      DMODEL, DMODEL, DMODEL, NH, 0, 0, 0, 0, 0, 0);
  gemm128<0><<<dim3(16, 32, 1), 256, 0, stream>>>(X, Wvt, Vb, vb, 1.0f,
      DMODEL, DMODEL, DMODEL, NH, 0, 0, 0, 0, 0, 0);

  // 3. V transpose per (b,n): [s][h] -> [h][s]
  transpose_v<<<dim3(64, 4, 32), tb, 0, stream>>>(Vb, VT);

  // 4. logits = Q K^T + bias2d  -> fp32 into probs region of d_out
  gemm128<1><<<dim3(16, 16, 32), 256, 0, stream>>>(Qb, Kb, out_probs, bias2d, 1.0f,
      HDIM, NH, NH, T_SEQ,
      (long long)T_SEQ * NH, HDIM,
      (long long)T_SEQ * NH, HDIM,
      (long long)16 * T_SEQ * T_SEQ, (long long)T_SEQ * T_SEQ);

  // 5. softmax rows, in place (exact fp32 probs)
  softmax_rows<<<32 * T_SEQ, 256, 0, stream>>>(out_probs);

  // 6. context = probs @ V   (A = fp32 probs reg-staged to f16)
  gemm128<2><<<dim3(1, 16, 32), 256, 0, stream>>>(out_probs, VT, CTX, nullptr, 1.0f,
      T_SEQ, T_SEQ, T_SEQ, NH,
      (long long)16 * T_SEQ * T_SEQ, (long long)T_SEQ * T_SEQ,
      (long long)16 * HDIM * T_SEQ, (long long)HDIM * T_SEQ,
      (long long)T_SEQ * NH, HDIM);

  // 7. data = context @ O^T + o_bias -> fp32 d_out
  gemm128<3><<<dim3(16, 32, 1), 256, 0, stream>>>(CTX, Wo, out_data, ob, 1.0f,
      NH, NH, NH, DMODEL, 0, 0, 0, 0, 0, 0);
}